// Round 8
// baseline (189.864 us; speedup 1.0000x reference)
//
#include <hip/hip_runtime.h>

#define N_IMG 9216
#define DFEAT 1024
#define NBP 36           // 256-row panels
#define NPAIR2 666       // 36*37/2 triangular panel-pairs

typedef __attribute__((ext_vector_type(8))) short short8;
typedef __attribute__((ext_vector_type(4))) float floatx4;
typedef __attribute__((ext_vector_type(16))) float floatx16;
typedef __attribute__((ext_vector_type(4))) int intx4;
typedef __attribute__((ext_vector_type(8))) int intx8;

// exp2-folded constants: sim = exp2(delta - gamma * rcp(1+u))
//   delta_ij = Pi*Pj          (P = sqrt(s) * C2, C2 = sqrt(2*log2e/1024))
//   gamma_ij = s~i + s~j + delta_ij   (s~ = s * C1, C1 = log2e/1024)
// fp4 path: Gram g = sum(z_i z_j), z = 32*normalized -> u = g/1024;
// rcp(1+u) = 1024*rcp(1024+g).
#define C1F 0.0014088818759657845f
#define C2F 0.05308355472172724f

__device__ __forceinline__ void async_copy16(const void* g, void* l) {
  __builtin_amdgcn_global_load_lds((const __attribute__((address_space(1))) void*)g,
                                   (__attribute__((address_space(3))) void*)l,
                                   16, 0, 0);
}

__device__ __forceinline__ unsigned short f2bf(float x) {
  union { float f; unsigned u; } a; a.f = x;
  unsigned u = a.u;
  u += 0x7fffu + ((u >> 16) & 1u);   // round-to-nearest-even
  return (unsigned short)(u >> 16);
}

// ---- fp4 e2m1 quantizer (RNE midpoints), values {0,.5,1,1.5,2,3,4,6} ----
__device__ __forceinline__ unsigned q4(float z) {
  unsigned sg = (__float_as_uint(z) >> 28) & 8u;
  float a = fabsf(z);
  unsigned c = (a < 0.25f) ? 0u : (a < 0.75f) ? 1u : (a < 1.25f) ? 2u :
               (a < 1.75f) ? 3u : (a < 2.5f)  ? 4u : (a < 3.5f)  ? 5u :
               (a < 5.0f)  ? 6u : 7u;
  return c | sg;
}
__device__ __forceinline__ unsigned short pk4(float4 v, float sc) {
  unsigned b0 = q4(v.x * sc) | (q4(v.y * sc) << 4);
  unsigned b1 = q4(v.z * sc) | (q4(v.w * sc) << 4);
  return (unsigned short)(b0 | (b1 << 8));
}

// ---- kernel 1: fp32 -> fp4 fragment-tiled + s~/P; also W1^T bf16; init sums ----
// tiled layout: fbT[rt][kb][r32][32B], rt=row>>5 (288 tiles), kb=k>>6 (16),
// r32=row&31; one (rt,kb) slab-chunk = 1024 B = one wave's coalesced frag.
__global__ __launch_bounds__(256) void convert_prep(const float* __restrict__ f,
                                                    const float* __restrict__ W1,
                                                    unsigned char* __restrict__ fbT,
                                                    float* __restrict__ sL,
                                                    float* __restrict__ pL,
                                                    unsigned short* __restrict__ W1t,
                                                    double* __restrict__ sums,
                                                    unsigned* __restrict__ ctr) {
  int b = blockIdx.x, t = threadIdx.x;
  if (b < 2304) {
    int lane = t & 63, wave = t >> 6;
    int row = b * 4 + wave;                      // one wave per row
    const float4* src = (const float4*)f + (size_t)row * 256;
    float4 v0 = src[lane], v1 = src[64 + lane], v2 = src[128 + lane], v3 = src[192 + lane];
    float s = v0.x * v0.x + v0.y * v0.y + v0.z * v0.z + v0.w * v0.w
            + v1.x * v1.x + v1.y * v1.y + v1.z * v1.z + v1.w * v1.w
            + v2.x * v2.x + v2.y * v2.y + v2.z * v2.z + v2.w * v2.w
            + v3.x * v3.x + v3.y * v3.y + v3.z * v3.z + v3.w * v3.w;
#pragma unroll
    for (int off = 32; off > 0; off >>= 1) s += __shfl_xor(s, off, 64);
    float zsc = rsqrtf(s) * 32.f;                // z ~ N(0,1)
    unsigned short u0 = pk4(v0, zsc), u1 = pk4(v1, zsc),
                   u2 = pk4(v2, zsc), u3 = pk4(v3, zsc);
    // lane holds elems 256j+4*lane..+3 -> kb_j = 4j + (lane>>4), byte 2*(lane&15)
    unsigned char* tb = fbT + (size_t)(row >> 5) * 16384 + (row & 31) * 32 + (lane & 15) * 2;
    int ko = (lane >> 4) * 1024;
    *(unsigned short*)(tb + ko) = u0;
    *(unsigned short*)(tb + ko + 4096) = u1;
    *(unsigned short*)(tb + ko + 8192) = u2;
    *(unsigned short*)(tb + ko + 12288) = u3;
    if (lane == 0) {
      sL[row] = s * C1F;
      pL[row] = sqrtf(s) * C2F;
    }
  } else {
    int j = b - 2304;                            // W1 column j -> W1t row j
    if (j == 0) {
      if (t < 2) sums[t] = 0.0;
      if (t == 2) *ctr = 0u;                     // completion counter for mlp
    }
    for (int k = t; k < DFEAT; k += 256)
      W1t[(size_t)j * DFEAT + k] = f2bf(W1[(size_t)k * 128 + j]);
  }
}

// ---- kernel 2: Gram via MX-fp4 MFMA, barrier-free, 128x128 REGISTER tile ----
// All 7 prior structures pinned at ~16-19 B/cy/CU memory throughput ->
// time = bytes/(fixed BW). Fix: arithmetic intensity. Block 256x256, 4 waves,
// wave (wave&1, wave>>1) owns a 128x128 output = acc[4][4] f32x16 (256 VGPR).
// Per K-step: 16 MFMA vs 8 x 16B loads = 2:1 (double R7's 1:1); total loaded
// bytes 672 -> 341 MB. 1 wave/SIMD (~470 regs) -- acceptable per R5's finding
// that extra waves don't raise the pinned BW. Depth-2 register pipeline keeps
// 16 loads/wave in flight (64 KB/CU, parity with R7). Zero K-loop barriers.
__global__ __launch_bounds__(256) void gram_sim(const unsigned char* __restrict__ fbT,
                                                const float* __restrict__ sL,
                                                const float* __restrict__ pL,
                                                double* __restrict__ sums) {
  __shared__ float sA[256], pA[256], sB[256], pB[256];
  __shared__ float wpart[4];

  int bid = blockIdx.x, t = threadIdx.x, lane = t & 63, wave = t >> 6;
  // bijective XCD slice swizzle (666 = 8*83 + 2)
  int xcd = bid & 7, ii = bid >> 3;
  int L = (xcd < 2 ? xcd * 84 : 168 + (xcd - 2) * 83) + ii;
  // decode triangular, bcol-major: panel bcol has bcol+1 rows (proven in R2)
  int rem = L, bcol = 0;
  while (rem > bcol) { rem -= (bcol + 1); bcol++; }
  int brow = rem;                                 // brow <= bcol

  sA[t] = sL[brow * 256 + t]; pA[t] = pL[brow * 256 + t];
  sB[t] = sL[bcol * 256 + t]; pB[t] = pL[bcol * 256 + t];
  __syncthreads();

  const int r32 = lane & 31, kh = lane >> 5;
  const int loff = r32 * 32 + kh * 16;
  const int wr = (wave & 1) * 128, wc = (wave >> 1) * 128;

  // 8 slab pointers: A slabs brow*8 + (wave&1)*4 + mi, B slabs bcol*8 + (wave>>1)*4 + ni
  const unsigned char* pa[4];
  const unsigned char* pb[4];
#pragma unroll
  for (int mi = 0; mi < 4; mi++)
    pa[mi] = fbT + (size_t)(brow * 8 + (wave & 1) * 4 + mi) * 16384 + loff;
#pragma unroll
  for (int ni = 0; ni < 4; ni++)
    pb[ni] = fbT + (size_t)(bcol * 8 + (wave >> 1) * 4 + ni) * 16384 + loff;

  floatx16 acc[4][4];
#pragma unroll
  for (int mi = 0; mi < 4; mi++)
#pragma unroll
    for (int ni = 0; ni < 4; ni++)
#pragma unroll
      for (int e = 0; e < 16; e++) acc[mi][ni][e] = 0.f;

  // fp4 operands use only the low 4 regs of the i32x8; zero high half ONCE
  union u8x { intx8 v8; intx4 q[2]; };
  u8x A8[4], B8[4];
#pragma unroll
  for (int i = 0; i < 4; i++) {
    A8[i].q[1] = (intx4){0, 0, 0, 0};
    B8[i].q[1] = (intx4){0, 0, 0, 0};
  }

  // depth-2 software pipeline: 3 register buffer sets, loads issue 2 iters ahead
  intx4 bA[3][4], bB[3][4];
#define LDSET(s, kb)                                                          \
  {                                                                           \
    const int o = (kb) * 1024;                                                \
    bA[s][0] = *(const intx4*)(pa[0] + o); bA[s][1] = *(const intx4*)(pa[1] + o); \
    bA[s][2] = *(const intx4*)(pa[2] + o); bA[s][3] = *(const intx4*)(pa[3] + o); \
    bB[s][0] = *(const intx4*)(pb[0] + o); bB[s][1] = *(const intx4*)(pb[1] + o); \
    bB[s][2] = *(const intx4*)(pb[2] + o); bB[s][3] = *(const intx4*)(pb[3] + o); \
  }
  LDSET(0, 0)
  LDSET(1, 1)
#pragma unroll
  for (int kb = 0; kb < 16; kb++) {
    const int cur = kb % 3, nxt = (kb + 2) % 3;
    if (kb < 14) LDSET(nxt, kb + 2)
#pragma unroll
    for (int i = 0; i < 4; i++) {
      A8[i].q[0] = bA[cur][i];
      B8[i].q[0] = bB[cur][i];
    }
#pragma unroll
    for (int mi = 0; mi < 4; mi++)
#pragma unroll
      for (int ni = 0; ni < 4; ni++)
        acc[mi][ni] = __builtin_amdgcn_mfma_scale_f32_32x32x64_f8f6f4(
            A8[mi].v8, B8[ni].v8, acc[mi][ni], 4, 4,   // FMT fp4 / fp4
            0, 0x7F7F7F7F, 0, 0x7F7F7F7F);             // scales = 1.0
  }
#undef LDSET

  // epilogue: g ~= 1024*cos. C/D layout col=lane&31, row=(reg&3)+8*(reg>>2)+4*kh
  const bool diag = (brow == bcol);
  float lsum = 0.f;
#pragma unroll
  for (int ni = 0; ni < 4; ni++) {
    int j_loc = wc + ni * 32 + r32;
    float sj = sB[j_loc], pj = pB[j_loc];
#pragma unroll
    for (int mi = 0; mi < 4; mi++) {
      int rbase = wr + mi * 32 + 4 * kh;
#pragma unroll
      for (int reg = 0; reg < 16; reg++) {
        int i_loc = rbase + (reg & 3) + 8 * (reg >> 2);
        float g = acc[mi][ni][reg];
        float si = sA[i_loc], pi = pA[i_loc];
        float r = __builtin_amdgcn_rcpf(1024.f + g);
        float del = pi * pj;
        float gam = si + sj + del;
        float sim = __builtin_amdgcn_exp2f(fmaf(-1024.f, gam * r, del));
        if (!diag) {
          lsum += sim;
        } else {
          lsum += (i_loc < j_loc) ? 2.f * sim : (i_loc == j_loc ? 1.f : 0.f);
        }
      }
    }
  }
  if (!diag) lsum *= 2.f;                         // brow<bcol: all i<j, count x2
#pragma unroll
  for (int off = 32; off > 0; off >>= 1) lsum += __shfl_down(lsum, off, 64);
  if (lane == 0) wpart[wave] = lsum;
  __syncthreads();
  if (t == 0)
    atomicAdd(&sums[0], (double)(wpart[0] + wpart[1] + wpart[2] + wpart[3]));
}

// ---- kernel 3: full MLP, 32 rows/block (288 blocks); dbuf-pipelined K-loop;
//      folds finalize via completion counter ----
__global__ __launch_bounds__(256) void mlp_full(const float* __restrict__ f,
                                                const unsigned short* __restrict__ W1t,
                                                const float* __restrict__ scores,
                                                const float* __restrict__ W1,
                                                const float* __restrict__ b1,
                                                const float* __restrict__ g1,
                                                const float* __restrict__ be1,
                                                const float* __restrict__ W2, const float* __restrict__ b2,
                                                const float* __restrict__ g2, const float* __restrict__ be2,
                                                const float* __restrict__ W3, const float* __restrict__ b3,
                                                double* __restrict__ sums,
                                                unsigned* __restrict__ ctr,
                                                float* __restrict__ out) {
  int r0 = blockIdx.x * 32;

  __shared__ __align__(16) float As32[2 * 32 * 64];         // 16 KB dbuf, XOR swz
  __shared__ __align__(16) unsigned short Bs[2 * 128 * 64]; // 32 KB dbuf, XOR swz
  __shared__ float h1s[32][128];                            // 16 KB
  __shared__ float h2s[32][65];                             // 8.3 KB
  __shared__ float sc[32], b1s[128], g1s[128], be1s[128], wls[128], ls[32];

  int t = threadIdx.x, lane = t & 63, wave = t >> 6;
  if (t < 32) sc[t] = scores[r0 + t];
  if (t < 128) {
    b1s[t] = b1[t]; g1s[t] = g1[t]; be1s[t] = be1[t];
    wls[t] = W1[(size_t)DFEAT * 128 + t];
  }
  __syncthreads();   // drain preamble loads: vmcnt clean before counted pipeline

  floatx4 acc[4];
#pragma unroll
  for (int b = 0; b < 4; b++) acc[b] = (floatx4){0.f, 0.f, 0.f, 0.f};

  const int wr = (wave & 1) * 16, wc = (wave >> 1) * 64;

  // 6 async_copy16 per thread per K-step (2 A + 4 B)
#define MSTAGE(buf, kk)                                                     \
  {                                                                         \
    const int k0_ = (kk) * 64;                                              \
    int c = t, rA = c >> 4, p = c & 15, l = p ^ (rA & 15);                  \
    async_copy16(f + (size_t)(r0 + rA) * DFEAT + k0_ + l * 4,               \
                 (char*)As32 + (buf) * 8192 + c * 16);                      \
    c = t + 256; rA = c >> 4; p = c & 15; l = p ^ (rA & 15);                \
    async_copy16(f + (size_t)(r0 + rA) * DFEAT + k0_ + l * 4,               \
                 (char*)As32 + (buf) * 8192 + c * 16);                      \
    _Pragma("unroll")                                                       \
    for (int q2 = 0; q2 < 4; q2++) {                                        \
      int cc = t + q2 * 256, rB = cc >> 3, pp = cc & 7, ll = pp ^ (rB & 7); \
      async_copy16(W1t + (size_t)rB * DFEAT + k0_ + ll * 8,                 \
                   (char*)Bs + (buf) * 16384 + cc * 16);                    \
    }                                                                       \
  }

  MSTAGE(0, 0)
  MSTAGE(1, 1)                                    // 12 loads outstanding/thread
  for (int kk = 0; kk < 16; kk++) {
    if (kk < 15) asm volatile("s_waitcnt vmcnt(6)" ::: "memory");
    else         asm volatile("s_waitcnt vmcnt(0)" ::: "memory");
    __builtin_amdgcn_s_barrier();                 // kstep-kk stage visible
    __builtin_amdgcn_sched_barrier(0);
    const int bufF = (kk & 1) * 2048;             // float offset into As32
    const int bufS = (kk & 1) * 8192;             // ushort offset into Bs

    const int mrow = lane & 15;
#pragma unroll
    for (int ks = 0; ks < 2; ks++) {
      const int kq = ks * 32 + (lane >> 4) * 8;
      short8 a, b[4];
      {
        int row = wr + mrow;
        int l0 = kq >> 2;
        int p0 = l0 ^ (row & 15), p1 = (l0 + 1) ^ (row & 15);
        float4 f0 = *(const float4*)&As32[bufF + row * 64 + p0 * 4];
        float4 f1 = *(const float4*)&As32[bufF + row * 64 + p1 * 4];
        a[0] = (short)f2bf(f0.x); a[1] = (short)f2bf(f0.y);
        a[2] = (short)f2bf(f0.z); a[3] = (short)f2bf(f0.w);
        a[4] = (short)f2bf(f1.x); a[5] = (short)f2bf(f1.y);
        a[6] = (short)f2bf(f1.z); a[7] = (short)f2bf(f1.w);
      }
#pragma unroll
      for (int nt = 0; nt < 4; nt++) {
        int row = wc + nt * 16 + mrow;
        int p = (kq >> 3) ^ (row & 7);
        b[nt] = *(const short8*)&Bs[bufS + row * 64 + p * 8];
      }
#pragma unroll
      for (int nt = 0; nt < 4; nt++)
        acc[nt] = __builtin_amdgcn_mfma_f32_16x16x32_bf16(a, b[nt], acc[nt], 0, 0, 0);
    }
    __builtin_amdgcn_sched_barrier(0);
    __builtin_amdgcn_s_barrier();                 // all reads of buf done
    __builtin_amdgcn_sched_barrier(0);
    if (kk < 14) MSTAGE((kk & 1), kk + 2)
  }
#undef MSTAGE

  const float inv = 1.0f / sqrtf(1.0f + 1e-5f);
  const int rq = (lane >> 4) * 4, cn = lane & 15;
#pragma unroll
  for (int nt = 0; nt < 4; nt++) {
    int j = wc + nt * 16 + cn;
    float bj = b1s[j], gj = g1s[j] * inv, bej = be1s[j], wj = wls[j];
#pragma unroll
    for (int rr = 0; rr < 4; rr++) {
      int iL = wr + rq + rr;
      float pre = acc[nt][rr] + sc[iL] * wj + bj;
      h1s[iL][j] = fmaxf(gj * pre + bej, 0.f);
    }
  }
  __syncthreads();

  // layer 2: 128 -> 64. j = t&63, 8 rows/thread (broadcast LDS reads)
  {
    int j = t & 63, rg = (t >> 6) * 8;
    float a2[8];
#pragma unroll
    for (int rr = 0; rr < 8; rr++) a2[rr] = 0.f;
    for (int k = 0; k < 128; k++) {
      float w = W2[k * 64 + j];
#pragma unroll
      for (int rr = 0; rr < 8; rr++) a2[rr] = fmaf(h1s[rg + rr][k], w, a2[rr]);
    }
    float scv = g2[j] * inv, bi = b2[j], be = be2[j];
#pragma unroll
    for (int rr = 0; rr < 8; rr++)
      h2s[rg + rr][j] = fmaxf(scv * (a2[rr] + bi) + be, 0.f);
  }
  __syncthreads();

  // layer 3: 64 -> 1 + sigmoid
  if (t < 32) {
    float z = b3[0];
#pragma unroll
    for (int k = 0; k < 64; k++) z = fmaf(h2s[t][k], W3[k], z);
    ls[t] = 1.f / (1.f + __expf(-z));
  }
  __syncthreads();
  if (t == 0) {
    float s = 0.f;
#pragma unroll
    for (int iL = 0; iL < 32; iL++) s += ls[iL];
    atomicAdd(&sums[1], (double)s);
    // folded finalize: gram ran earlier in-stream, so sums[0] is complete;
    // last mlp block to arrive combines.
    __threadfence();
    unsigned prev = atomicAdd(ctr, 1u);
    if (prev == 287u) {
      __threadfence();
      double s0 = ((volatile double*)sums)[0];
      double s1 = ((volatile double*)sums)[1];
      out[0] = (float)((s1 / (double)N_IMG) * (s0 / ((double)N_IMG * (double)N_IMG)));
    }
  }
}

extern "C" void kernel_launch(void* const* d_in, const int* in_sizes, int n_in,
                              void* d_out, int out_size, void* d_ws, size_t ws_size,
                              hipStream_t stream) {
  const float* f      = (const float*)d_in[0];
  const float* scores = (const float*)d_in[1];
  const float* W1 = (const float*)d_in[2];
  const float* b1 = (const float*)d_in[3];
  const float* g1 = (const float*)d_in[4];
  const float* be1 = (const float*)d_in[5];
  const float* W2 = (const float*)d_in[6];
  const float* b2 = (const float*)d_in[7];
  const float* g2 = (const float*)d_in[8];
  const float* be2 = (const float*)d_in[9];
  const float* W3 = (const float*)d_in[10];
  const float* b3 = (const float*)d_in[11];

  // workspace layout (~5.06 MB total)
  char* ws = (char*)d_ws;
  unsigned char* fbT  = (unsigned char*)ws;                  // 4,718,592 B (fp4 tiled)
  float* sL           = (float*)(ws + 4718592);              // 36,864 B  (s * C1)
  float* pL           = (float*)(ws + 4755456);              // 36,864 B  (sqrt(s) * C2)
  unsigned short* W1t = (unsigned short*)(ws + 4792320);     // 262,144 B
  double* sums        = (double*)(ws + 5054464);             // 16 B
  unsigned* ctr       = (unsigned*)(ws + 5054480);           // 4 B (completion)

  convert_prep<<<2432, 256, 0, stream>>>(f, W1, fbT, sL, pL, W1t, sums, ctr);
  gram_sim<<<NPAIR2, 256, 0, stream>>>(fbT, sL, pL, sums);
  mlp_full<<<288, 256, 0, stream>>>(f, W1t, scores, W1, b1, g1, be1,
                                    W2, b2, g2, be2, W3, b3, sums, ctr,
                                    (float*)d_out);
}

// Round 9
// 184.835 us; speedup vs baseline: 1.0272x; 1.0272x over previous
//
#include <hip/hip_runtime.h>

#define N_IMG 9216
#define DFEAT 1024
#define NBR2 72          // 128-row panels
#define NPAIR4 2628      // 72*73/2 triangular panel-pairs

typedef __attribute__((ext_vector_type(8))) short short8;
typedef __attribute__((ext_vector_type(4))) float floatx4;
typedef __attribute__((ext_vector_type(16))) float floatx16;
typedef __attribute__((ext_vector_type(4))) int intx4;
typedef __attribute__((ext_vector_type(8))) int intx8;

// exp2-folded constants: sim = exp2(delta - gamma * rcp(1+u))
//   delta_ij = Pi*Pj          (P = sqrt(s) * C2, C2 = sqrt(2*log2e/1024))
//   gamma_ij = s~i + s~j + delta_ij   (s~ = s * C1, C1 = log2e/1024)
// fp4 path: Gram g = sum(z_i z_j), z = 32*normalized -> u = g/1024;
// rcp(1+u) = 1024*rcp(1024+g).
#define C1F 0.0014088818759657845f
#define C2F 0.05308355472172724f

__device__ __forceinline__ void async_copy16(const void* g, void* l) {
  __builtin_amdgcn_global_load_lds((const __attribute__((address_space(1))) void*)g,
                                   (__attribute__((address_space(3))) void*)l,
                                   16, 0, 0);
}

__device__ __forceinline__ unsigned short f2bf(float x) {
  union { float f; unsigned u; } a; a.f = x;
  unsigned u = a.u;
  u += 0x7fffu + ((u >> 16) & 1u);   // round-to-nearest-even
  return (unsigned short)(u >> 16);
}

// ---- fp4 e2m1 quantizer (RNE midpoints), values {0,.5,1,1.5,2,3,4,6} ----
__device__ __forceinline__ unsigned q4(float z) {
  unsigned sg = (__float_as_uint(z) >> 28) & 8u;
  float a = fabsf(z);
  unsigned c = (a < 0.25f) ? 0u : (a < 0.75f) ? 1u : (a < 1.25f) ? 2u :
               (a < 1.75f) ? 3u : (a < 2.5f)  ? 4u : (a < 3.5f)  ? 5u :
               (a < 5.0f)  ? 6u : 7u;
  return c | sg;
}
__device__ __forceinline__ unsigned short pk4(float4 v, float sc) {
  unsigned b0 = q4(v.x * sc) | (q4(v.y * sc) << 4);
  unsigned b1 = q4(v.z * sc) | (q4(v.w * sc) << 4);
  return (unsigned short)(b0 | (b1 << 8));
}

// ---- kernel 1: fp32 -> fp4 fragment-tiled + s~/P; also W1^T bf16; init sums ----
// tiled layout: fbT[rt][kb][r32][32B], rt=row>>5 (288 tiles), kb=k>>6 (16),
// r32=row&31; one (rt,kb) slab-chunk = 1024 B = one wave's coalesced frag.
__global__ __launch_bounds__(256) void convert_prep(const float* __restrict__ f,
                                                    const float* __restrict__ W1,
                                                    unsigned char* __restrict__ fbT,
                                                    float* __restrict__ sL,
                                                    float* __restrict__ pL,
                                                    unsigned short* __restrict__ W1t,
                                                    double* __restrict__ sums,
                                                    unsigned* __restrict__ ctr) {
  int b = blockIdx.x, t = threadIdx.x;
  if (b < 2304) {
    int lane = t & 63, wave = t >> 6;
    int row = b * 4 + wave;                      // one wave per row
    const float4* src = (const float4*)f + (size_t)row * 256;
    float4 v0 = src[lane], v1 = src[64 + lane], v2 = src[128 + lane], v3 = src[192 + lane];
    float s = v0.x * v0.x + v0.y * v0.y + v0.z * v0.z + v0.w * v0.w
            + v1.x * v1.x + v1.y * v1.y + v1.z * v1.z + v1.w * v1.w
            + v2.x * v2.x + v2.y * v2.y + v2.z * v2.z + v2.w * v2.w
            + v3.x * v3.x + v3.y * v3.y + v3.z * v3.z + v3.w * v3.w;
#pragma unroll
    for (int off = 32; off > 0; off >>= 1) s += __shfl_xor(s, off, 64);
    float zsc = rsqrtf(s) * 32.f;                // z ~ N(0,1)
    unsigned short u0 = pk4(v0, zsc), u1 = pk4(v1, zsc),
                   u2 = pk4(v2, zsc), u3 = pk4(v3, zsc);
    // lane holds elems 256j+4*lane..+3 -> kb_j = 4j + (lane>>4), byte 2*(lane&15)
    unsigned char* tb = fbT + (size_t)(row >> 5) * 16384 + (row & 31) * 32 + (lane & 15) * 2;
    int ko = (lane >> 4) * 1024;
    *(unsigned short*)(tb + ko) = u0;
    *(unsigned short*)(tb + ko + 4096) = u1;
    *(unsigned short*)(tb + ko + 8192) = u2;
    *(unsigned short*)(tb + ko + 12288) = u3;
    if (lane == 0) {
      sL[row] = s * C1F;
      pL[row] = sqrtf(s) * C2F;
    }
  } else {
    int j = b - 2304;                            // W1 column j -> W1t row j
    if (j == 0) {
      if (t < 2) sums[t] = 0.0;
      if (t == 2) *ctr = 0u;                     // completion counter for mlp
    }
    for (int k = t; k < DFEAT; k += 256)
      W1t[(size_t)j * DFEAT + k] = f2bf(W1[(size_t)k * 128 + j]);
  }
}

// ---- kernel 2: Gram via MX-fp4 MFMA, per-wave LDS pipeline, depth-3 ----
// R7 structure (supertile order, 4 waves/block, 64x64/wave, acc[2][2], zero
// cross-wave barriers) with the staging moved from registers to PER-WAVE
// private LDS via global_load_lds. R7's 858 cy/K-step decomposed to
// load-latency/depth with depth-2 -> deepen to 3 at zero VGPR cost:
// each wave owns 3 x 4 KB LDS buffers, counted s_waitcnt vmcnt(8/4/0)
// (per-wave counter -> no barriers), identity ds_read_b128 at lane*16
// (fragment permutation pre-applied on the per-lane GLOBAL address).
// In-flight/CU: 12 waves x 12 KB = 144 KB (3x R7's coverage).
__global__ __launch_bounds__(256, 3) void gram_sim(const unsigned char* __restrict__ fbT,
                                                   const float* __restrict__ sL,
                                                   const float* __restrict__ pL,
                                                   double* __restrict__ sums) {
  __shared__ __align__(1024) unsigned char stg[4 * 3 * 4096];  // 48 KB: [wave][buf][4KB]
  __shared__ float sA[128], pA[128], sB[128], pB[128];
  __shared__ float wpart[4];

  int bid = blockIdx.x, t = threadIdx.x, lane = t & 63, wave = t >> 6;
  // bijective XCD slice swizzle (2628 = 8*328 + 4): XCD x owns a contiguous
  // range of L, so it walks supertiles sequentially.
  int xcd = bid & 7, ii = bid >> 3;
  int L = (xcd < 4 ? xcd * 329 : 1316 + (xcd - 4) * 328) + ii;
  // supertile decode: 9 panel-groups of 8; group BJ holds BJ offdiag
  // supertiles (64 blocks each, BI<BJ) then the diag supertile (36 blocks).
  int rem = L, BJ = 0;
  for (;;) {
    int c = 64 * BJ + 36;
    if (rem < c) break;
    rem -= c; BJ++;
  }
  int brow, bcol;
  if (rem < 64 * BJ) {                            // offdiag supertile (BI, BJ)
    int BI = rem >> 6, r2 = rem & 63;
    brow = BI * 8 + (r2 >> 3);
    bcol = BJ * 8 + (r2 & 7);
  } else {                                        // diag supertile (BJ, BJ)
    int r2 = rem - 64 * BJ, bl = 0;               // triangular 8x8, bcol-major
    while (r2 > bl) { r2 -= (bl + 1); bl++; }
    brow = BJ * 8 + r2;
    bcol = BJ * 8 + bl;
  }

  if (t < 128) { sA[t] = sL[brow * 128 + t]; pA[t] = pL[brow * 128 + t]; }
  else { int u = t - 128; sB[u] = sL[bcol * 128 + u]; pB[u] = pL[bcol * 128 + u]; }
  __syncthreads();                                // drains vmcnt before pipeline

  const int r32 = lane & 31, kh = lane >> 5;
  const int loff = r32 * 32 + kh * 16;            // fragment perm, on GLOBAL side
  const int wr = (wave & 1) * 64, wc = (wave >> 1) * 64;

  const unsigned char* ga0 = fbT + (size_t)(brow * 4 + (wr >> 5)) * 16384 + loff;
  const unsigned char* ga1 = ga0 + 16384;
  const unsigned char* gb0 = fbT + (size_t)(bcol * 4 + (wc >> 5)) * 16384 + loff;
  const unsigned char* gb1 = gb0 + 16384;

  char* lbase = (char*)stg + wave * 12288;        // wave-uniform LDS dest base
  const char* lread = lbase + lane * 16;          // identity read: own 16 B

  // 4 global_load_lds per K-step; HW writes lds[base + lane*16] = g[src(lane)]
#define STAGE(buf, kb)                                        \
  {                                                           \
    char* d = lbase + (buf) * 4096;                           \
    const int o = (kb) * 1024;                                \
    async_copy16(ga0 + o, d);                                 \
    async_copy16(ga1 + o, d + 1024);                          \
    async_copy16(gb0 + o, d + 2048);                          \
    async_copy16(gb1 + o, d + 3072);                          \
  }

  floatx16 acc[2][2];
#pragma unroll
  for (int mi = 0; mi < 2; mi++)
#pragma unroll
    for (int ni = 0; ni < 2; ni++)
#pragma unroll
      for (int e = 0; e < 16; e++) acc[mi][ni][e] = 0.f;

  // fp4 operands use only the low 4 regs of the i32x8; zero high half ONCE
  union u8x { intx8 v8; intx4 q[2]; };
  u8x A8[2], B8[2];
#pragma unroll
  for (int mi = 0; mi < 2; mi++) A8[mi].q[1] = (intx4){0, 0, 0, 0};
#pragma unroll
  for (int ni = 0; ni < 2; ni++) B8[ni].q[1] = (intx4){0, 0, 0, 0};

  STAGE(0, 0)
  STAGE(1, 1)
  STAGE(2, 2)                                     // 12 loads outstanding / wave
#pragma unroll
  for (int kb = 0; kb < 16; kb++) {
    // outstanding: steps kb..min(kb+2,15); wait for step kb's 4 loads
    if (kb <= 13)      asm volatile("s_waitcnt vmcnt(8)" ::: "memory");
    else if (kb == 14) asm volatile("s_waitcnt vmcnt(4)" ::: "memory");
    else               asm volatile("s_waitcnt vmcnt(0)" ::: "memory");
    __builtin_amdgcn_sched_barrier(0);
    const int buf = kb % 3;
    const char* rb = lread + buf * 4096;
    A8[0].q[0] = *(const intx4*)(rb);
    A8[1].q[0] = *(const intx4*)(rb + 1024);
    B8[0].q[0] = *(const intx4*)(rb + 2048);
    B8[1].q[0] = *(const intx4*)(rb + 3072);
#pragma unroll
    for (int mi = 0; mi < 2; mi++)
#pragma unroll
      for (int ni = 0; ni < 2; ni++)
        acc[mi][ni] = __builtin_amdgcn_mfma_scale_f32_32x32x64_f8f6f4(
            A8[mi].v8, B8[ni].v8, acc[mi][ni], 4, 4,   // FMT fp4 / fp4
            0, 0x7F7F7F7F, 0, 0x7F7F7F7F);             // scales = 1.0
    // refill same buf for step kb+3 (reads of buf completed: ds_read data is
    // consumed by the MFMAs above; gload lands >=300cy later)
    if (kb <= 12) STAGE(buf, kb + 3)
  }
#undef STAGE

  // epilogue: g ~= 1024*cos. C/D layout col=lane&31, row=(reg&3)+8*(reg>>2)+4*kh
  const bool diag = (brow == bcol);
  float lsum = 0.f;
#pragma unroll
  for (int ni = 0; ni < 2; ni++) {
    int j_loc = wc + ni * 32 + r32;
    float sj = sB[j_loc], pj = pB[j_loc];
#pragma unroll
    for (int mi = 0; mi < 2; mi++) {
      int rbase = wr + mi * 32 + 4 * kh;
#pragma unroll
      for (int reg = 0; reg < 16; reg++) {
        int i_loc = rbase + (reg & 3) + 8 * (reg >> 2);
        float g = acc[mi][ni][reg];
        float si = sA[i_loc], pi = pA[i_loc];
        float r = __builtin_amdgcn_rcpf(1024.f + g);
        float del = pi * pj;
        float gam = si + sj + del;
        float sim = __builtin_amdgcn_exp2f(fmaf(-1024.f, gam * r, del));
        if (!diag) {
          lsum += sim;
        } else {
          lsum += (i_loc < j_loc) ? 2.f * sim : (i_loc == j_loc ? 1.f : 0.f);
        }
      }
    }
  }
  if (!diag) lsum *= 2.f;                         // brow<bcol: all i<j, count x2
#pragma unroll
  for (int off = 32; off > 0; off >>= 1) lsum += __shfl_down(lsum, off, 64);
  if (lane == 0) wpart[wave] = lsum;
  __syncthreads();
  if (t == 0)
    atomicAdd(&sums[0], (double)(wpart[0] + wpart[1] + wpart[2] + wpart[3]));
}

// ---- kernel 3: full MLP, 32 rows/block (288 blocks); dbuf-pipelined K-loop;
//      folds finalize via completion counter ----
__global__ __launch_bounds__(256) void mlp_full(const float* __restrict__ f,
                                                const unsigned short* __restrict__ W1t,
                                                const float* __restrict__ scores,
                                                const float* __restrict__ W1,
                                                const float* __restrict__ b1,
                                                const float* __restrict__ g1,
                                                const float* __restrict__ be1,
                                                const float* __restrict__ W2, const float* __restrict__ b2,
                                                const float* __restrict__ g2, const float* __restrict__ be2,
                                                const float* __restrict__ W3, const float* __restrict__ b3,
                                                double* __restrict__ sums,
                                                unsigned* __restrict__ ctr,
                                                float* __restrict__ out) {
  int r0 = blockIdx.x * 32;

  __shared__ __align__(16) float As32[2 * 32 * 64];         // 16 KB dbuf, XOR swz
  __shared__ __align__(16) unsigned short Bs[2 * 128 * 64]; // 32 KB dbuf, XOR swz
  __shared__ float h1s[32][128];                            // 16 KB
  __shared__ float h2s[32][65];                             // 8.3 KB
  __shared__ float sc[32], b1s[128], g1s[128], be1s[128], wls[128], ls[32];

  int t = threadIdx.x, lane = t & 63, wave = t >> 6;
  if (t < 32) sc[t] = scores[r0 + t];
  if (t < 128) {
    b1s[t] = b1[t]; g1s[t] = g1[t]; be1s[t] = be1[t];
    wls[t] = W1[(size_t)DFEAT * 128 + t];
  }
  __syncthreads();   // drain preamble loads: vmcnt clean before counted pipeline

  floatx4 acc[4];
#pragma unroll
  for (int b = 0; b < 4; b++) acc[b] = (floatx4){0.f, 0.f, 0.f, 0.f};

  const int wr = (wave & 1) * 16, wc = (wave >> 1) * 64;

  // 6 async_copy16 per thread per K-step (2 A + 4 B)
#define MSTAGE(buf, kk)                                                     \
  {                                                                         \
    const int k0_ = (kk) * 64;                                              \
    int c = t, rA = c >> 4, p = c & 15, l = p ^ (rA & 15);                  \
    async_copy16(f + (size_t)(r0 + rA) * DFEAT + k0_ + l * 4,               \
                 (char*)As32 + (buf) * 8192 + c * 16);                      \
    c = t + 256; rA = c >> 4; p = c & 15; l = p ^ (rA & 15);                \
    async_copy16(f + (size_t)(r0 + rA) * DFEAT + k0_ + l * 4,               \
                 (char*)As32 + (buf) * 8192 + c * 16);                      \
    _Pragma("unroll")                                                       \
    for (int q2 = 0; q2 < 4; q2++) {                                        \
      int cc = t + q2 * 256, rB = cc >> 3, pp = cc & 7, ll = pp ^ (rB & 7); \
      async_copy16(W1t + (size_t)rB * DFEAT + k0_ + ll * 8,                 \
                   (char*)Bs + (buf) * 16384 + cc * 16);                    \
    }                                                                       \
  }

  MSTAGE(0, 0)
  MSTAGE(1, 1)                                    // 12 loads outstanding/thread
  for (int kk = 0; kk < 16; kk++) {
    if (kk < 15) asm volatile("s_waitcnt vmcnt(6)" ::: "memory");
    else         asm volatile("s_waitcnt vmcnt(0)" ::: "memory");
    __builtin_amdgcn_s_barrier();                 // kstep-kk stage visible
    __builtin_amdgcn_sched_barrier(0);
    const int bufF = (kk & 1) * 2048;             // float offset into As32
    const int bufS = (kk & 1) * 8192;             // ushort offset into Bs

    const int mrow = lane & 15;
#pragma unroll
    for (int ks = 0; ks < 2; ks++) {
      const int kq = ks * 32 + (lane >> 4) * 8;
      short8 a, b[4];
      {
        int row = wr + mrow;
        int l0 = kq >> 2;
        int p0 = l0 ^ (row & 15), p1 = (l0 + 1) ^ (row & 15);
        float4 f0 = *(const float4*)&As32[bufF + row * 64 + p0 * 4];
        float4 f1 = *(const float4*)&As32[bufF + row * 64 + p1 * 4];
        a[0] = (short)f2bf(f0.x); a[1] = (short)f2bf(f0.y);
        a[2] = (short)f2bf(f0.z); a[3] = (short)f2bf(f0.w);
        a[4] = (short)f2bf(f1.x); a[5] = (short)f2bf(f1.y);
        a[6] = (short)f2bf(f1.z); a[7] = (short)f2bf(f1.w);
      }
#pragma unroll
      for (int nt = 0; nt < 4; nt++) {
        int row = wc + nt * 16 + mrow;
        int p = (kq >> 3) ^ (row & 7);
        b[nt] = *(const short8*)&Bs[bufS + row * 64 + p * 8];
      }
#pragma unroll
      for (int nt = 0; nt < 4; nt++)
        acc[nt] = __builtin_amdgcn_mfma_f32_16x16x32_bf16(a, b[nt], acc[nt], 0, 0, 0);
    }
    __builtin_amdgcn_sched_barrier(0);
    __builtin_amdgcn_s_barrier();                 // all reads of buf done
    __builtin_amdgcn_sched_barrier(0);
    if (kk < 14) MSTAGE((kk & 1), kk + 2)
  }
#undef MSTAGE

  const float inv = 1.0f / sqrtf(1.0f + 1e-5f);
  const int rq = (lane >> 4) * 4, cn = lane & 15;
#pragma unroll
  for (int nt = 0; nt < 4; nt++) {
    int j = wc + nt * 16 + cn;
    float bj = b1s[j], gj = g1s[j] * inv, bej = be1s[j], wj = wls[j];
#pragma unroll
    for (int rr = 0; rr < 4; rr++) {
      int iL = wr + rq + rr;
      float pre = acc[nt][rr] + sc[iL] * wj + bj;
      h1s[iL][j] = fmaxf(gj * pre + bej, 0.f);
    }
  }
  __syncthreads();

  // layer 2: 128 -> 64. j = t&63, 8 rows/thread (broadcast LDS reads)
  {
    int j = t & 63, rg = (t >> 6) * 8;
    float a2[8];
#pragma unroll
    for (int rr = 0; rr < 8; rr++) a2[rr] = 0.f;
    for (int k = 0; k < 128; k++) {
      float w = W2[k * 64 + j];
#pragma unroll
      for (int rr = 0; rr < 8; rr++) a2[rr] = fmaf(h1s[rg + rr][k], w, a2[rr]);
    }
    float scv = g2[j] * inv, bi = b2[j], be = be2[j];
#pragma unroll
    for (int rr = 0; rr < 8; rr++)
      h2s[rg + rr][j] = fmaxf(scv * (a2[rr] + bi) + be, 0.f);
  }
  __syncthreads();

  // layer 3: 64 -> 1 + sigmoid
  if (t < 32) {
    float z = b3[0];
#pragma unroll
    for (int k = 0; k < 64; k++) z = fmaf(h2s[t][k], W3[k], z);
    ls[t] = 1.f / (1.f + __expf(-z));
  }
  __syncthreads();
  if (t == 0) {
    float s = 0.f;
#pragma unroll
    for (int iL = 0; iL < 32; iL++) s += ls[iL];
    atomicAdd(&sums[1], (double)s);
    // folded finalize: gram ran earlier in-stream, so sums[0] is complete;
    // last mlp block to arrive combines.
    __threadfence();
    unsigned prev = atomicAdd(ctr, 1u);
    if (prev == 287u) {
      __threadfence();
      double s0 = ((volatile double*)sums)[0];
      double s1 = ((volatile double*)sums)[1];
      out[0] = (float)((s1 / (double)N_IMG) * (s0 / ((double)N_IMG * (double)N_IMG)));
    }
  }
}

extern "C" void kernel_launch(void* const* d_in, const int* in_sizes, int n_in,
                              void* d_out, int out_size, void* d_ws, size_t ws_size,
                              hipStream_t stream) {
  const float* f      = (const float*)d_in[0];
  const float* scores = (const float*)d_in[1];
  const float* W1 = (const float*)d_in[2];
  const float* b1 = (const float*)d_in[3];
  const float* g1 = (const float*)d_in[4];
  const float* be1 = (const float*)d_in[5];
  const float* W2 = (const float*)d_in[6];
  const float* b2 = (const float*)d_in[7];
  const float* g2 = (const float*)d_in[8];
  const float* be2 = (const float*)d_in[9];
  const float* W3 = (const float*)d_in[10];
  const float* b3 = (const float*)d_in[11];

  // workspace layout (~5.06 MB total)
  char* ws = (char*)d_ws;
  unsigned char* fbT  = (unsigned char*)ws;                  // 4,718,592 B (fp4 tiled)
  float* sL           = (float*)(ws + 4718592);              // 36,864 B  (s * C1)
  float* pL           = (float*)(ws + 4755456);              // 36,864 B  (sqrt(s) * C2)
  unsigned short* W1t = (unsigned short*)(ws + 4792320);     // 262,144 B
  double* sums        = (double*)(ws + 5054464);             // 16 B
  unsigned* ctr       = (unsigned*)(ws + 5054480);           // 4 B (completion)

  convert_prep<<<2432, 256, 0, stream>>>(f, W1, fbT, sL, pL, W1t, sums, ctr);
  gram_sim<<<NPAIR4, 256, 0, stream>>>(fbT, sL, pL, sums);
  mlp_full<<<288, 256, 0, stream>>>(f, W1t, scores, W1, b1, g1, be1,
                                    W2, b2, g2, be2, W3, b3, sums, ctr,
                                    (float*)d_out);
}